// Round 1
// baseline (4096.641 us; speedup 1.0000x reference)
//
#include <hip/hip_runtime.h>

// ChildSumTreeGRU: BRANCH=4, DEPTH=8, N=87381, X=H=512.
// Tree layout: depth-d nodes contiguous at S[d]=(4^d-1)/3; children of p = 4p+1..4p+4.
// Level l nodes = depth 8-l. h written once per node at its level -> compute in d_out.

#define NNODES 87381
#define NINT   21845   // internal nodes = rows 0..21844
#define NLEAF  65536   // leaf nodes = rows 21845..87380

__device__ __forceinline__ float sigmoidf_(float x) { return 1.0f / (1.0f + __expf(-x)); }

// C[m,n] = epi( sum_k A[m,k]*B[n,k] ) ; A: Mx512, B: Noutx512 row-major, K=512.
// EPI 0: plain (z_e)
// EPI 1: C = sigmoid(wx[g0+m, n] + acc) * A[m,n]          (rh = r * h_sum; Nout=512)
// EPI 2: C = tanh(wx[g0+m, 512+n] + acc)                   (h_cand)
// EPI 3: C = acc + bias[n]                                  (wx_int)
template <int EPI>
__global__ __launch_bounds__(256) void gemm_k(const float* __restrict__ A,
                                              const float* __restrict__ B,
                                              float* __restrict__ C, int ldc, int M,
                                              const float* __restrict__ wx, int g0,
                                              const float* __restrict__ bias) {
  __shared__ float As[16][132];
  __shared__ float Bs[16][132];
  const int t = threadIdx.x;
  const int tx = t & 15, ty = t >> 4;
  const int m0 = blockIdx.x * 128;
  const int n0 = blockIdx.y * 128;
  float acc[8][8];
#pragma unroll
  for (int i = 0; i < 8; ++i)
#pragma unroll
    for (int j = 0; j < 8; ++j) acc[i][j] = 0.0f;

  const int lr = t >> 2;         // 0..63
  const int kq = (t & 3) << 2;   // 0,4,8,12

  for (int k0 = 0; k0 < 512; k0 += 16) {
#pragma unroll
    for (int h = 0; h < 2; ++h) {
      const int row = lr + h * 64;
      float4 va = make_float4(0.f, 0.f, 0.f, 0.f);
      if (m0 + row < M) va = *(const float4*)(A + (size_t)(m0 + row) * 512 + k0 + kq);
      As[kq + 0][row] = va.x; As[kq + 1][row] = va.y;
      As[kq + 2][row] = va.z; As[kq + 3][row] = va.w;
      float4 vb = *(const float4*)(B + (size_t)(n0 + row) * 512 + k0 + kq);
      Bs[kq + 0][row] = vb.x; Bs[kq + 1][row] = vb.y;
      Bs[kq + 2][row] = vb.z; Bs[kq + 3][row] = vb.w;
    }
    __syncthreads();
#pragma unroll
    for (int kk = 0; kk < 16; ++kk) {
      const float4 a0 = *(const float4*)&As[kk][ty * 8];
      const float4 a1 = *(const float4*)&As[kk][ty * 8 + 4];
      const float4 b0 = *(const float4*)&Bs[kk][tx * 8];
      const float4 b1 = *(const float4*)&Bs[kk][tx * 8 + 4];
      const float a[8] = {a0.x, a0.y, a0.z, a0.w, a1.x, a1.y, a1.z, a1.w};
      const float b[8] = {b0.x, b0.y, b0.z, b0.w, b1.x, b1.y, b1.z, b1.w};
#pragma unroll
      for (int i = 0; i < 8; ++i)
#pragma unroll
        for (int j = 0; j < 8; ++j) acc[i][j] = fmaf(a[i], b[j], acc[i][j]);
    }
    __syncthreads();
  }

#pragma unroll
  for (int i = 0; i < 8; ++i) {
    const int m = m0 + ty * 8 + i;
    if (m >= M) break;
#pragma unroll
    for (int j = 0; j < 8; ++j) {
      const int n = n0 + tx * 8 + j;
      const float v = acc[i][j];
      if (EPI == 0) {
        C[(size_t)m * ldc + n] = v;
      } else if (EPI == 1) {
        const float wr = wx[(size_t)(g0 + m) * 1536 + n];
        C[(size_t)m * ldc + n] = sigmoidf_(wr + v) * A[(size_t)m * 512 + n];
      } else if (EPI == 2) {
        const float wh = wx[(size_t)(g0 + m) * 1536 + 512 + n];
        C[(size_t)m * ldc + n] = tanhf(wh + v);
      } else {
        C[(size_t)m * ldc + n] = v + bias[n];
      }
    }
  }
}

// Leaf: h = (1 - sigmoid(wzx)) * tanh(whx), fusing BOTH gate GEMMs (skips wrx).
// BM=128, BN=64, micro 8x4 with two accumulators.
__global__ __launch_bounds__(256) void leaf_k(const float* __restrict__ x,
                                              const float* __restrict__ W,
                                              const float* __restrict__ bw,
                                              float* __restrict__ out) {
  __shared__ float As[16][132];
  __shared__ float Bh[16][68];
  __shared__ float Bz[16][68];
  const int t = threadIdx.x;
  const int tx = t & 15, ty = t >> 4;
  const int m0 = blockIdx.x * 128;   // leaf-local
  const int n0 = blockIdx.y * 64;
  float acch[8][4], accz[8][4];
#pragma unroll
  for (int i = 0; i < 8; ++i)
#pragma unroll
    for (int j = 0; j < 4; ++j) { acch[i][j] = 0.f; accz[i][j] = 0.f; }

  const int lr = t >> 2;
  const int kq = (t & 3) << 2;
  const float* Aleaf = x + (size_t)NINT * 512;

  for (int k0 = 0; k0 < 512; k0 += 16) {
#pragma unroll
    for (int h = 0; h < 2; ++h) {
      const int row = lr + h * 64;
      float4 va = *(const float4*)(Aleaf + (size_t)(m0 + row) * 512 + k0 + kq);
      As[kq + 0][row] = va.x; As[kq + 1][row] = va.y;
      As[kq + 2][row] = va.z; As[kq + 3][row] = va.w;
    }
    {
      float4 vh = *(const float4*)(W + (size_t)(512 + n0 + lr) * 512 + k0 + kq);
      Bh[kq + 0][lr] = vh.x; Bh[kq + 1][lr] = vh.y;
      Bh[kq + 2][lr] = vh.z; Bh[kq + 3][lr] = vh.w;
      float4 vz = *(const float4*)(W + (size_t)(1024 + n0 + lr) * 512 + k0 + kq);
      Bz[kq + 0][lr] = vz.x; Bz[kq + 1][lr] = vz.y;
      Bz[kq + 2][lr] = vz.z; Bz[kq + 3][lr] = vz.w;
    }
    __syncthreads();
#pragma unroll
    for (int kk = 0; kk < 16; ++kk) {
      const float4 a0 = *(const float4*)&As[kk][ty * 8];
      const float4 a1 = *(const float4*)&As[kk][ty * 8 + 4];
      const float4 h4 = *(const float4*)&Bh[kk][tx * 4];
      const float4 z4 = *(const float4*)&Bz[kk][tx * 4];
      const float a[8] = {a0.x, a0.y, a0.z, a0.w, a1.x, a1.y, a1.z, a1.w};
      const float bh[4] = {h4.x, h4.y, h4.z, h4.w};
      const float bz[4] = {z4.x, z4.y, z4.z, z4.w};
#pragma unroll
      for (int i = 0; i < 8; ++i)
#pragma unroll
        for (int j = 0; j < 4; ++j) {
          acch[i][j] = fmaf(a[i], bh[j], acch[i][j]);
          accz[i][j] = fmaf(a[i], bz[j], accz[i][j]);
        }
    }
    __syncthreads();
  }
#pragma unroll
  for (int i = 0; i < 8; ++i) {
    const int m = m0 + ty * 8 + i;
#pragma unroll
    for (int j = 0; j < 4; ++j) {
      const int n = n0 + tx * 4 + j;
      const float wh = acch[i][j] + bw[512 + n];
      const float wz = accz[i][j] + bw[1024 + n];
      out[(size_t)(NINT + m) * 512 + n] = (1.0f - sigmoidf_(wz)) * tanhf(wh);
    }
  }
}

// h_sum[i,:] = sum of 4 children rows (children of parent i start at cbase+4i)
__global__ __launch_bounds__(256) void child_sum_k(const float* __restrict__ out,
                                                   int cbase, int nl,
                                                   float* __restrict__ hsum) {
  const int idx = blockIdx.x * 256 + threadIdx.x;
  if (idx >= nl * 128) return;
  const int i = idx >> 7;
  const int jq = (idx & 127) << 2;
  const float* b = out + (size_t)(cbase + 4 * i) * 512 + jq;
  const float4 a = *(const float4*)(b);
  const float4 c = *(const float4*)(b + 512);
  const float4 d = *(const float4*)(b + 1024);
  const float4 e = *(const float4*)(b + 1536);
  float4 s;
  s.x = a.x + c.x + d.x + e.x;
  s.y = a.y + c.y + d.y + e.y;
  s.z = a.z + c.z + d.z + e.z;
  s.w = a.w + c.w + d.w + e.w;
  *(float4*)(hsum + (size_t)i * 512 + jq) = s;
}

// h[p] = sum_c z_e[c]*h[c] + (1 - sum_c sigmoid(z_e[c]+wzx[p])) * h_cand[p]
// h_cand currently sits in out[p]; overwritten in place.
__global__ __launch_bounds__(256) void combine_k(float* __restrict__ out,
                                                 const float* __restrict__ ze,
                                                 const float* __restrict__ wx,
                                                 int pbase, int cbase, int nl) {
  const int idx = blockIdx.x * 256 + threadIdx.x;
  if (idx >= nl * 128) return;
  const int i = idx >> 7;
  const int jq = (idx & 127) << 2;
  const float4 wz = *(const float4*)(wx + (size_t)(pbase + i) * 1536 + 1024 + jq);
  float4 hpre = make_float4(0.f, 0.f, 0.f, 0.f);
  float4 zs = make_float4(0.f, 0.f, 0.f, 0.f);
#pragma unroll
  for (int c = 0; c < 4; ++c) {
    const float4 z = *(const float4*)(ze + (size_t)(4 * i + c) * 512 + jq);
    const float4 h = *(const float4*)(out + (size_t)(cbase + 4 * i + c) * 512 + jq);
    hpre.x = fmaf(z.x, h.x, hpre.x);
    hpre.y = fmaf(z.y, h.y, hpre.y);
    hpre.z = fmaf(z.z, h.z, hpre.z);
    hpre.w = fmaf(z.w, h.w, hpre.w);
    zs.x += sigmoidf_(z.x + wz.x);
    zs.y += sigmoidf_(z.y + wz.y);
    zs.z += sigmoidf_(z.z + wz.z);
    zs.w += sigmoidf_(z.w + wz.w);
  }
  float* po = out + (size_t)(pbase + i) * 512 + jq;
  const float4 hc = *(const float4*)po;
  float4 r;
  r.x = hpre.x + (1.f - zs.x) * hc.x;
  r.y = hpre.y + (1.f - zs.y) * hc.y;
  r.z = hpre.z + (1.f - zs.z) * hc.z;
  r.w = hpre.w + (1.f - zs.w) * hc.w;
  *(float4*)po = r;
}

extern "C" void kernel_launch(void* const* d_in, const int* in_sizes, int n_in,
                              void* d_out, int out_size, void* d_ws, size_t ws_size,
                              hipStream_t stream) {
  const float* x   = (const float*)d_in[0];
  const float* Ww  = (const float*)d_in[1];
  const float* bw  = (const float*)d_in[2];
  const float* Ur  = (const float*)d_in[3];
  const float* Uhc = (const float*)d_in[4];
  const float* Uz  = (const float*)d_in[5];
  float* out = (float*)d_out;

  float* ws = (float*)d_ws;
  float* wx_int = ws;                          // 21845 * 1536
  float* ze     = wx_int + (size_t)NINT * 1536; // 65536 * 512
  float* hsum   = ze + (size_t)65536 * 512;     // 16384 * 512
  float* rh     = hsum + (size_t)16384 * 512;   // 16384 * 512

  // wx for internal nodes (all 3 gates, +bias)
  {
    dim3 g((NINT + 127) / 128, 12);
    gemm_k<3><<<g, 256, 0, stream>>>(x, Ww, wx_int, 1536, NINT, nullptr, 0, bw);
  }
  // leaves: fused gates -> h_leaf directly into out
  {
    dim3 g(NLEAF / 128, 512 / 64);
    leaf_k<<<g, 256, 0, stream>>>(x, Ww, bw, out);
  }

  static const int S[10] = {0, 1, 5, 21, 85, 341, 1365, 5461, 21845, 87381};
  for (int l = 1; l <= 8; ++l) {
    const int d = 8 - l;
    const int pbase = S[d];
    const int nl = S[d + 1] - S[d];
    const int cbase = S[d + 1];
    const int el = 4 * nl;

    child_sum_k<<<(nl * 128 + 255) / 256, 256, 0, stream>>>(out, cbase, nl, hsum);

    dim3 gr((nl + 127) / 128, 4);
    // rh = sigmoid(wrx + hsum@Ur^T) * hsum
    gemm_k<1><<<gr, 256, 0, stream>>>(hsum, Ur, rh, 512, nl, wx_int, pbase, nullptr);
    // h_cand = tanh(whx + rh@Uhc^T) -> out[parent rows] (temporary)
    gemm_k<2><<<gr, 256, 0, stream>>>(rh, Uhc, out + (size_t)pbase * 512, 512, nl,
                                      wx_int, pbase, nullptr);
    // z_e = h_children @ Uz^T  (children are a contiguous block)
    dim3 gz((el + 127) / 128, 4);
    gemm_k<0><<<gz, 256, 0, stream>>>(out + (size_t)cbase * 512, Uz, ze, 512, el,
                                      nullptr, 0, nullptr);

    combine_k<<<(nl * 128 + 255) / 256, 256, 0, stream>>>(out, ze, wx_int, pbase,
                                                          cbase, nl);
  }
}

// Round 3
// 1925.271 us; speedup vs baseline: 2.1278x; 2.1278x over previous
//
#include <hip/hip_runtime.h>

// ChildSumTreeGRU: BRANCH=4, DEPTH=8, N=87381, X=H=512.
// depth-d nodes contiguous at S[d]=(4^d-1)/3; children of p = 4p+1..4p+4.
// R2: split-bf16 MFMA everywhere; A-operand split-on-stage from fp32;
//     all LDS ops b64-aligned (stride 36 ushorts); fused leaf gate kernel.

#define NNODES 87381
#define NINT   21845
#define NLEAF  65536

typedef __attribute__((ext_vector_type(8))) __bf16 bf16x8;
typedef __attribute__((ext_vector_type(4))) float f32x4;

union FU { bf16x8 v; ushort4 u[2]; };

__device__ __forceinline__ float sigmoidf_(float x) { return 1.0f / (1.0f + __expf(-x)); }
__device__ __forceinline__ float tanhf_(float x) { return 2.0f / (1.0f + __expf(-2.0f * x)) - 1.0f; }

__device__ __forceinline__ unsigned short bf_rne(float f) {
  unsigned int u = __float_as_uint(f);
  unsigned int r = u + 0x7FFFu + ((u >> 16) & 1u);
  return (unsigned short)(r >> 16);
}
__device__ __forceinline__ void split2(float f, unsigned short& h, unsigned short& l) {
  h = bf_rne(f);
  l = bf_rne(f - __uint_as_float((unsigned int)h << 16));
}

// ---------------- split fp32 -> (hi, lo) bf16 (weights only) ----------------
__global__ __launch_bounds__(256) void split_k(const float* __restrict__ s,
                                               unsigned short* __restrict__ hi,
                                               unsigned short* __restrict__ lo, int n4) {
  int i = blockIdx.x * 256 + threadIdx.x;
  if (i >= n4) return;
  float4 v = *(const float4*)(s + (size_t)i * 4);
  ushort4 h, l;
  split2(v.x, h.x, l.x); split2(v.y, h.y, l.y);
  split2(v.z, h.z, l.z); split2(v.w, h.w, l.w);
  *(ushort4*)(hi + (size_t)i * 4) = h;
  *(ushort4*)(lo + (size_t)i * 4) = l;
}

// ---------------- MFMA split-bf16 GEMM, A split-on-stage from fp32 ----------------
// C[m,n] = epi( sum_k A[m,k]*B[n,k] ), K=512. tile 128x128, BK=32, 4 waves,
// wave = 64x64 = 4x4 tiles of 16x16x32. 3 MFMAs per tile pair (hh, hl, lh).
// EPI 0: plain store                      (z_e)
// EPI 1: C = sigmoid(wx[g0+m,n]+acc)*Afp[m,n]    (rh)
// EPI 2: C = tanh(wx[g0+m,512+n]+acc)            (h_cand)
// EPI 3: C = acc + bias[n]                       (wx)
template <int EPI>
__global__ __launch_bounds__(256) void mgemm(const float* __restrict__ A,
                                             const unsigned short* __restrict__ Bh,
                                             const unsigned short* __restrict__ Bl,
                                             float* __restrict__ C, int ldc, int M,
                                             const float* __restrict__ wx, int g0,
                                             const float* __restrict__ bias,
                                             const float* __restrict__ Afp) {
  __shared__ unsigned short As_h[128][36];
  __shared__ unsigned short As_l[128][36];
  __shared__ unsigned short Bs_h[128][36];
  __shared__ unsigned short Bs_l[128][36];
  const int t = threadIdx.x;
  const int lane = t & 63, wave = t >> 6;
  const int wm = wave & 1, wn = wave >> 1;
  const int m0 = blockIdx.x * 128, n0 = blockIdx.y * 128;

  f32x4 acc[4][4];
#pragma unroll
  for (int i = 0; i < 4; ++i)
#pragma unroll
    for (int j = 0; j < 4; ++j) acc[i][j] = (f32x4){0.f, 0.f, 0.f, 0.f};

  const int r0 = t >> 2, r1 = r0 + 64;  // rows staged by this thread
  const int q0 = (t & 3) * 8;           // k-offset (elements)
  const int fr = lane & 15, fq = (lane >> 4) * 8;

  for (int k0 = 0; k0 < 512; k0 += 32) {
#pragma unroll
    for (int hh = 0; hh < 2; ++hh) {
      const int r = hh ? r1 : r0;
      // A: fp32 -> split in-register
      const int gr = m0 + r;
      float4 f0 = make_float4(0.f, 0.f, 0.f, 0.f), f1 = f0;
      if (gr < M) {
        const float* ap = A + (size_t)gr * 512 + k0 + q0;
        f0 = *(const float4*)ap;
        f1 = *(const float4*)(ap + 4);
      }
      ushort4 h0, l0, h1, l1;
      split2(f0.x, h0.x, l0.x); split2(f0.y, h0.y, l0.y);
      split2(f0.z, h0.z, l0.z); split2(f0.w, h0.w, l0.w);
      split2(f1.x, h1.x, l1.x); split2(f1.y, h1.y, l1.y);
      split2(f1.z, h1.z, l1.z); split2(f1.w, h1.w, l1.w);
      *(ushort4*)&As_h[r][q0] = h0; *(ushort4*)&As_h[r][q0 + 4] = h1;
      *(ushort4*)&As_l[r][q0] = l0; *(ushort4*)&As_l[r][q0 + 4] = l1;
      // B: pre-split bf16
      const unsigned short* bp = Bh + (size_t)(n0 + r) * 512 + k0 + q0;
      const unsigned short* lp = Bl + (size_t)(n0 + r) * 512 + k0 + q0;
      const uint4 b4 = *(const uint4*)bp;
      const uint4 l4 = *(const uint4*)lp;
      *(uint2*)&Bs_h[r][q0] = make_uint2(b4.x, b4.y);
      *(uint2*)&Bs_h[r][q0 + 4] = make_uint2(b4.z, b4.w);
      *(uint2*)&Bs_l[r][q0] = make_uint2(l4.x, l4.y);
      *(uint2*)&Bs_l[r][q0 + 4] = make_uint2(l4.z, l4.w);
    }
    __syncthreads();

    bf16x8 ah[4], al[4], bh[4], bl[4];
#pragma unroll
    for (int mt = 0; mt < 4; ++mt) {
      const int row = wm * 64 + mt * 16 + fr;
      FU fa, fb;
      fa.u[0] = *(const ushort4*)&As_h[row][fq];
      fa.u[1] = *(const ushort4*)&As_h[row][fq + 4];
      ah[mt] = fa.v;
      fb.u[0] = *(const ushort4*)&As_l[row][fq];
      fb.u[1] = *(const ushort4*)&As_l[row][fq + 4];
      al[mt] = fb.v;
    }
#pragma unroll
    for (int nt = 0; nt < 4; ++nt) {
      const int row = wn * 64 + nt * 16 + fr;
      FU fa, fb;
      fa.u[0] = *(const ushort4*)&Bs_h[row][fq];
      fa.u[1] = *(const ushort4*)&Bs_h[row][fq + 4];
      bh[nt] = fa.v;
      fb.u[0] = *(const ushort4*)&Bs_l[row][fq];
      fb.u[1] = *(const ushort4*)&Bs_l[row][fq + 4];
      bl[nt] = fb.v;
    }
#pragma unroll
    for (int mt = 0; mt < 4; ++mt)
#pragma unroll
      for (int nt = 0; nt < 4; ++nt) {
        acc[mt][nt] = __builtin_amdgcn_mfma_f32_16x16x32_bf16(ah[mt], bh[nt], acc[mt][nt], 0, 0, 0);
        acc[mt][nt] = __builtin_amdgcn_mfma_f32_16x16x32_bf16(ah[mt], bl[nt], acc[mt][nt], 0, 0, 0);
        acc[mt][nt] = __builtin_amdgcn_mfma_f32_16x16x32_bf16(al[mt], bh[nt], acc[mt][nt], 0, 0, 0);
      }
    __syncthreads();
  }

  // C/D layout: col=lane&15, row=(lane>>4)*4+reg
  const int ecol = lane & 15;
  const int erow = (lane >> 4) * 4;
#pragma unroll
  for (int mt = 0; mt < 4; ++mt) {
#pragma unroll
    for (int nt = 0; nt < 4; ++nt) {
      const int col = n0 + wn * 64 + nt * 16 + ecol;
#pragma unroll
      for (int r = 0; r < 4; ++r) {
        const int row = m0 + wm * 64 + mt * 16 + erow + r;
        if (row >= M) continue;
        const float v = acc[mt][nt][r];
        if (EPI == 0) {
          C[(size_t)row * ldc + col] = v;
        } else if (EPI == 1) {
          const float rg = sigmoidf_(wx[(size_t)(g0 + row) * 1536 + col] + v);
          C[(size_t)row * ldc + col] = rg * Afp[(size_t)row * 512 + col];
        } else if (EPI == 2) {
          C[(size_t)row * ldc + col] = tanhf_(wx[(size_t)(g0 + row) * 1536 + 512 + col] + v);
        } else {
          C[(size_t)row * ldc + col] = v + bias[col];
        }
      }
    }
  }
}

// ---------------- fused leaf kernel: h = (1-sig(x@Wz^T+bz)) * tanh(x@Wh^T+bh) ----------------
// tile 128 rows x 64 cols, both gates accumulated; B-LDS rows 0..63 = h-gate, 64..127 = z-gate.
__global__ __launch_bounds__(256) void mleaf(const float* __restrict__ x,
                                             const unsigned short* __restrict__ Wh,
                                             const unsigned short* __restrict__ Wl,
                                             const float* __restrict__ bw,
                                             float* __restrict__ out) {
  __shared__ unsigned short As_h[128][36];
  __shared__ unsigned short As_l[128][36];
  __shared__ unsigned short Bs_h[128][36];
  __shared__ unsigned short Bs_l[128][36];
  const int t = threadIdx.x;
  const int lane = t & 63, wave = t >> 6;
  const int wm = wave & 1, wn = wave >> 1;
  const int m0 = blockIdx.x * 128, n0 = blockIdx.y * 64;

  f32x4 acch[4][2], accz[4][2];
#pragma unroll
  for (int i = 0; i < 4; ++i)
#pragma unroll
    for (int j = 0; j < 2; ++j) {
      acch[i][j] = (f32x4){0.f, 0.f, 0.f, 0.f};
      accz[i][j] = (f32x4){0.f, 0.f, 0.f, 0.f};
    }

  const int r0 = t >> 2, r1 = r0 + 64;
  const int q0 = (t & 3) * 8;
  const int fr = lane & 15, fq = (lane >> 4) * 8;
  const float* Ax = x + (size_t)NINT * 512;  // leaf rows

  for (int k0 = 0; k0 < 512; k0 += 32) {
#pragma unroll
    for (int hh = 0; hh < 2; ++hh) {
      const int r = hh ? r1 : r0;
      const float* ap = Ax + (size_t)(m0 + r) * 512 + k0 + q0;
      const float4 f0 = *(const float4*)ap;
      const float4 f1 = *(const float4*)(ap + 4);
      ushort4 h0, l0, h1, l1;
      split2(f0.x, h0.x, l0.x); split2(f0.y, h0.y, l0.y);
      split2(f0.z, h0.z, l0.z); split2(f0.w, h0.w, l0.w);
      split2(f1.x, h1.x, l1.x); split2(f1.y, h1.y, l1.y);
      split2(f1.z, h1.z, l1.z); split2(f1.w, h1.w, l1.w);
      *(ushort4*)&As_h[r][q0] = h0; *(ushort4*)&As_h[r][q0 + 4] = h1;
      *(ushort4*)&As_l[r][q0] = l0; *(ushort4*)&As_l[r][q0 + 4] = l1;
      // B row: r0 -> h-gate row 512+n0+r0 ; r1 -> z-gate row 1024+n0+r0
      const int br = hh ? (1024 + n0 + (r - 64)) : (512 + n0 + r);
      const uint4 b4 = *(const uint4*)(Wh + (size_t)br * 512 + k0 + q0);
      const uint4 l4 = *(const uint4*)(Wl + (size_t)br * 512 + k0 + q0);
      *(uint2*)&Bs_h[r][q0] = make_uint2(b4.x, b4.y);
      *(uint2*)&Bs_h[r][q0 + 4] = make_uint2(b4.z, b4.w);
      *(uint2*)&Bs_l[r][q0] = make_uint2(l4.x, l4.y);
      *(uint2*)&Bs_l[r][q0 + 4] = make_uint2(l4.z, l4.w);
    }
    __syncthreads();

    bf16x8 ah[4], al[4], bhh[2], bhl[2], bzh[2], bzl[2];
#pragma unroll
    for (int mt = 0; mt < 4; ++mt) {
      const int row = wm * 64 + mt * 16 + fr;
      FU fa, fb;
      fa.u[0] = *(const ushort4*)&As_h[row][fq];
      fa.u[1] = *(const ushort4*)&As_h[row][fq + 4];
      ah[mt] = fa.v;
      fb.u[0] = *(const ushort4*)&As_l[row][fq];
      fb.u[1] = *(const ushort4*)&As_l[row][fq + 4];
      al[mt] = fb.v;
    }
#pragma unroll
    for (int nt = 0; nt < 2; ++nt) {
      const int rh_ = wn * 32 + nt * 16 + fr;
      const int rz_ = 64 + wn * 32 + nt * 16 + fr;
      FU a, b, c, d;
      a.u[0] = *(const ushort4*)&Bs_h[rh_][fq];
      a.u[1] = *(const ushort4*)&Bs_h[rh_][fq + 4];
      bhh[nt] = a.v;
      b.u[0] = *(const ushort4*)&Bs_l[rh_][fq];
      b.u[1] = *(const ushort4*)&Bs_l[rh_][fq + 4];
      bhl[nt] = b.v;
      c.u[0] = *(const ushort4*)&Bs_h[rz_][fq];
      c.u[1] = *(const ushort4*)&Bs_h[rz_][fq + 4];
      bzh[nt] = c.v;
      d.u[0] = *(const ushort4*)&Bs_l[rz_][fq];
      d.u[1] = *(const ushort4*)&Bs_l[rz_][fq + 4];
      bzl[nt] = d.v;
    }
#pragma unroll
    for (int mt = 0; mt < 4; ++mt)
#pragma unroll
      for (int nt = 0; nt < 2; ++nt) {
        acch[mt][nt] = __builtin_amdgcn_mfma_f32_16x16x32_bf16(ah[mt], bhh[nt], acch[mt][nt], 0, 0, 0);
        acch[mt][nt] = __builtin_amdgcn_mfma_f32_16x16x32_bf16(ah[mt], bhl[nt], acch[mt][nt], 0, 0, 0);
        acch[mt][nt] = __builtin_amdgcn_mfma_f32_16x16x32_bf16(al[mt], bhh[nt], acch[mt][nt], 0, 0, 0);
        accz[mt][nt] = __builtin_amdgcn_mfma_f32_16x16x32_bf16(ah[mt], bzh[nt], accz[mt][nt], 0, 0, 0);
        accz[mt][nt] = __builtin_amdgcn_mfma_f32_16x16x32_bf16(ah[mt], bzl[nt], accz[mt][nt], 0, 0, 0);
        accz[mt][nt] = __builtin_amdgcn_mfma_f32_16x16x32_bf16(al[mt], bzh[nt], accz[mt][nt], 0, 0, 0);
      }
    __syncthreads();
  }

  const int ecol = lane & 15;
  const int erow = (lane >> 4) * 4;
#pragma unroll
  for (int mt = 0; mt < 4; ++mt) {
#pragma unroll
    for (int nt = 0; nt < 2; ++nt) {
      const int col = n0 + wn * 32 + nt * 16 + ecol;
      const float bh_ = bw[512 + col];
      const float bz_ = bw[1024 + col];
#pragma unroll
      for (int r = 0; r < 4; ++r) {
        const int row = m0 + wm * 64 + mt * 16 + erow + r;
        const float vh = acch[mt][nt][r] + bh_;
        const float vz = accz[mt][nt][r] + bz_;
        out[(size_t)(NINT + row) * 512 + col] = (1.f - sigmoidf_(vz)) * tanhf_(vh);
      }
    }
  }
}

// ---------------- child sum ----------------
__global__ __launch_bounds__(256) void child_sum_k(const float* __restrict__ out,
                                                   int cbase, int nl,
                                                   float* __restrict__ hsum) {
  const int idx = blockIdx.x * 256 + threadIdx.x;
  if (idx >= nl * 128) return;
  const int i = idx >> 7;
  const int jq = (idx & 127) << 2;
  const float* b = out + (size_t)(cbase + 4 * i) * 512 + jq;
  const float4 a = *(const float4*)(b);
  const float4 c = *(const float4*)(b + 512);
  const float4 d = *(const float4*)(b + 1024);
  const float4 e = *(const float4*)(b + 1536);
  float4 s;
  s.x = a.x + c.x + d.x + e.x;
  s.y = a.y + c.y + d.y + e.y;
  s.z = a.z + c.z + d.z + e.z;
  s.w = a.w + c.w + d.w + e.w;
  *(float4*)(hsum + (size_t)i * 512 + jq) = s;
}

// ---------------- combine ----------------
__global__ __launch_bounds__(256) void combine_k(float* __restrict__ out,
                                                 const float* __restrict__ ze,
                                                 const float* __restrict__ wx,
                                                 int pbase, int cbase, int nl) {
  const int idx = blockIdx.x * 256 + threadIdx.x;
  if (idx >= nl * 128) return;
  const int i = idx >> 7;
  const int jq = (idx & 127) << 2;
  const float4 wz = *(const float4*)(wx + (size_t)(pbase + i) * 1536 + 1024 + jq);
  float4 hpre = make_float4(0.f, 0.f, 0.f, 0.f);
  float4 zs = make_float4(0.f, 0.f, 0.f, 0.f);
#pragma unroll
  for (int c = 0; c < 4; ++c) {
    const float4 z = *(const float4*)(ze + (size_t)(4 * i + c) * 512 + jq);
    const float4 h = *(const float4*)(out + (size_t)(cbase + 4 * i + c) * 512 + jq);
    hpre.x = fmaf(z.x, h.x, hpre.x);
    hpre.y = fmaf(z.y, h.y, hpre.y);
    hpre.z = fmaf(z.z, h.z, hpre.z);
    hpre.w = fmaf(z.w, h.w, hpre.w);
    zs.x += sigmoidf_(z.x + wz.x);
    zs.y += sigmoidf_(z.y + wz.y);
    zs.z += sigmoidf_(z.z + wz.z);
    zs.w += sigmoidf_(z.w + wz.w);
  }
  float* po = out + (size_t)(pbase + i) * 512 + jq;
  const float4 hc = *(const float4*)po;
  float4 r;
  r.x = hpre.x + (1.f - zs.x) * hc.x;
  r.y = hpre.y + (1.f - zs.y) * hc.y;
  r.z = hpre.z + (1.f - zs.z) * hc.z;
  r.w = hpre.w + (1.f - zs.w) * hc.w;
  *(float4*)po = r;
}

extern "C" void kernel_launch(void* const* d_in, const int* in_sizes, int n_in,
                              void* d_out, int out_size, void* d_ws, size_t ws_size,
                              hipStream_t stream) {
  const float* x   = (const float*)d_in[0];
  const float* Ww  = (const float*)d_in[1];
  const float* bw  = (const float*)d_in[2];
  const float* Ur  = (const float*)d_in[3];
  const float* Uhc = (const float*)d_in[4];
  const float* Uz  = (const float*)d_in[5];
  float* out = (float*)d_out;

  // workspace: 134.2 (ze) + 134.2 (wx_int) + 33.6 (hsum) + 6.3 (weight splits) = 308.3 MB
  char* p = (char*)d_ws;
  float* ze = (float*)p;     p += (size_t)65536 * 512 * 4;
  float* rh = ze;            // alias: rh written/consumed before ze of the same level
  float* wx_int = (float*)p; p += (size_t)NINT * 1536 * 4;
  float* hsum = (float*)p;   p += (size_t)16384 * 512 * 4;
  unsigned short* W_hi = (unsigned short*)p;   p += (size_t)1536 * 512 * 2;
  unsigned short* W_lo = (unsigned short*)p;   p += (size_t)1536 * 512 * 2;
  unsigned short* Ur_hi = (unsigned short*)p;  p += (size_t)512 * 512 * 2;
  unsigned short* Ur_lo = (unsigned short*)p;  p += (size_t)512 * 512 * 2;
  unsigned short* Uhc_hi = (unsigned short*)p; p += (size_t)512 * 512 * 2;
  unsigned short* Uhc_lo = (unsigned short*)p; p += (size_t)512 * 512 * 2;
  unsigned short* Uz_hi = (unsigned short*)p;  p += (size_t)512 * 512 * 2;
  unsigned short* Uz_lo = (unsigned short*)p;  p += (size_t)512 * 512 * 2;

  // 1. split weights
  split_k<<<(1536 * 512 / 4 + 255) / 256, 256, 0, stream>>>(Ww, W_hi, W_lo, 1536 * 512 / 4);
  split_k<<<(512 * 512 / 4 + 255) / 256, 256, 0, stream>>>(Ur, Ur_hi, Ur_lo, 512 * 512 / 4);
  split_k<<<(512 * 512 / 4 + 255) / 256, 256, 0, stream>>>(Uhc, Uhc_hi, Uhc_lo, 512 * 512 / 4);
  split_k<<<(512 * 512 / 4 + 255) / 256, 256, 0, stream>>>(Uz, Uz_hi, Uz_lo, 512 * 512 / 4);

  // 2. wx for internal nodes (3 gates + bias)
  mgemm<3><<<dim3((NINT + 127) / 128, 12), 256, 0, stream>>>(
      x, W_hi, W_lo, wx_int, 1536, NINT, nullptr, 0, bw, nullptr);

  // 3. fused leaf h -> out
  mleaf<<<dim3(NLEAF / 128, 8), 256, 0, stream>>>(x, W_hi, W_lo, bw, out);

  static const int S[10] = {0, 1, 5, 21, 85, 341, 1365, 5461, 21845, 87381};
  for (int l = 1; l <= 8; ++l) {
    const int d = 8 - l;
    const int pbase = S[d];
    const int nl = S[d + 1] - S[d];
    const int cbase = S[d + 1];
    const int el = 4 * nl;

    child_sum_k<<<(nl * 128 + 255) / 256, 256, 0, stream>>>(out, cbase, nl, hsum);

    dim3 gr((nl + 127) / 128, 4);
    // rh = sigmoid(wrx + hsum@Ur^T) * hsum
    mgemm<1><<<gr, 256, 0, stream>>>(hsum, Ur_hi, Ur_lo, rh, 512, nl, wx_int, pbase,
                                     nullptr, hsum);
    // h_cand = tanh(whx + rh@Uhc^T) -> out[parent rows]
    mgemm<2><<<gr, 256, 0, stream>>>(rh, Uhc_hi, Uhc_lo, out + (size_t)pbase * 512, 512, nl,
                                     wx_int, pbase, nullptr, nullptr);
    // z_e = h_children @ Uz^T (overwrites rh region; rh is dead)
    dim3 gz((el + 127) / 128, 4);
    mgemm<0><<<gz, 256, 0, stream>>>(out + (size_t)cbase * 512, Uz_hi, Uz_lo, ze, 512, el,
                                     nullptr, 0, nullptr, nullptr);

    combine_k<<<(nl * 128 + 255) / 256, 256, 0, stream>>>(out, ze, wx_int, pbase, cbase, nl);
  }
}